// Round 1
// 489.658 us; speedup vs baseline: 1.1271x; 1.1271x over previous
//
#include <hip/hip_runtime.h>
#include <math.h>

#define D_ 96
#define H_ 128
#define W_ 128
#define NCH 64            // B*C = 2*32
#define CHUNKS 24         // 96 d-slices / 4 per chunk
#define SLICES_PER_CHUNK 4
#define F4_PER_CHUNK (SLICES_PER_CHUNK * H_ * W_ / 4)   // 16384

// clang native vector — __builtin_nontemporal_load requires scalar/native-vector,
// not HIP_vector_type<float,4>.
typedef float floatx4 __attribute__((ext_vector_type(4)));

// Kernel 1 (UNCHANGED from 549.7 µs best): per-(channel, d-chunk) partial reduction
// of {mass, sum(v*x), sum(v*y), sum(v*z)}. Streaming pass over 402.6 MB with
// NONTEMPORAL float4 loads (no L2/L3 allocate: avoids dirty-eviction writeback
// storms from the harness's 1.5 GiB poison fill + 402 MB input restore that
// immediately precede us in the timed window).
// Latency hiding is oversatisfied: 24 waves/CU x 16 outstanding 1KB wave-loads
// = ~384 KB in flight vs ~25-75 KB needed -> HBM-BW-floor (~64-70 us).
__global__ __launch_bounds__(256) void tooth_reduce_kernel(
        const float* __restrict__ seg, float* __restrict__ partials) {
    const int channel = blockIdx.y;   // b*32 + c
    const int chunk   = blockIdx.x;   // group of 4 d-slices
    const int tid     = threadIdx.x;

    const floatx4* __restrict__ p = reinterpret_cast<const floatx4*>(seg)
        + (size_t)channel * (D_ * H_ * W_ / 4)
        + (size_t)chunk * F4_PER_CHUNK;

    float m = 0.f, corr = 0.f, tj = 0.f, tk = 0.f;
    for (int jo = 0; jo < 4; jo++) {            // slice index within chunk
        float sk = 0.f;
        #pragma unroll
        for (int ji = 0; ji < 16; ji++) {       // 16 loads in flight
            floatx4 v = __builtin_nontemporal_load(&p[tid + ((jo * 16 + ji) << 8)]);
            float s = (v.x + v.y) + (v.z + v.w);
            m    += s;
            corr += v.y + 2.f * v.z + 3.f * v.w;     // intra-float4 x offsets
            tj   += s * (float)ji;                   // h-weight (affine part)
            sk   += s;
        }
        tk += sk * (float)jo;                        // slice (z) weight
    }
    const float wf = (float)((tid & 31) << 2);   // per-thread x base
    const float h0 = (float)(tid >> 5);          // per-thread h base
    const float dbase = (float)(chunk * SLICES_PER_CHUNK);
    float wx = fmaf(wf, m, corr);
    float wy = fmaf(h0, m, 8.f * tj);
    float wz = fmaf(dbase, m, tk);

    // wave64 shuffle reduction
    for (int off = 32; off > 0; off >>= 1) {
        m  += __shfl_down(m,  off, 64);
        wx += __shfl_down(wx, off, 64);
        wy += __shfl_down(wy, off, 64);
        wz += __shfl_down(wz, off, 64);
    }
    __shared__ float red[4][4];
    const int wave = tid >> 6;
    if ((tid & 63) == 0) {
        red[wave][0] = m; red[wave][1] = wx; red[wave][2] = wy; red[wave][3] = wz;
    }
    __syncthreads();
    if (tid == 0) {
        float M  = (red[0][0] + red[1][0]) + (red[2][0] + red[3][0]);
        float WX = (red[0][1] + red[1][1]) + (red[2][1] + red[3][1]);
        float WY = (red[0][2] + red[1][2]) + (red[2][2] + red[3][2]);
        float WZ = (red[0][3] + red[1][3]) + (red[2][3] + red[3][3]);
        float* o = partials + ((size_t)channel * CHUNKS + chunk) * 4;
        o[0] = M; o[1] = WX; o[2] = WY; o[3] = WZ;
    }
}

// Kernel 2: epilogue in double (variance must be two-pass at volume ~8e5).
// v2: WAVE-PARALLEL — the previous version ran ~4000 dependent f64 ops
// (incl. 56 serial sqrt_f64) on thread 0 alone (~5-10 us latency chain).
// Now: landmark on all 64 lanes, adjacent hinge on lanes 0-55, opposing+
// symmetric on lanes 0-31, anatomy variance on lanes 0-7, then one wave64
// shfl tree over the 7 partial terms. f64 reassociation error ~1e-16 rel
// -> identical f32 outputs.
__constant__ double TRIG_S[16] = {
    0.0, 0.20791169081775934, 0.40673664307580021, 0.58778525229247314,
    0.74314482547739424, 0.86602540378443865, 0.95105651629515353,
    0.99452189536827329, 0.99452189536827329, 0.95105651629515353,
    0.86602540378443865, 0.74314482547739424, 0.58778525229247314,
    0.40673664307580021, 0.20791169081775934, 0.0 };
__constant__ double TRIG_C[16] = {
    1.0, 0.9781476007338057, 0.91354545764260087, 0.80901699437494745,
    0.66913060635885824, 0.5, 0.30901699437494742, 0.10452846326765347,
    -0.10452846326765333, -0.30901699437494742, -0.5, -0.66913060635885824,
    -0.80901699437494745, -0.91354545764260087, -0.9781476007338057, -1.0 };
// tooth-type groups, flattened (0-indexed)
__constant__ int GRP_IDX[32] = {
    6, 7, 8, 9, 22, 23, 24, 25,
    5, 10, 21, 26,
    3, 4, 11, 12, 19, 20, 27, 28,
    0, 1, 2, 13, 14, 15, 16, 17, 18, 29, 30, 31 };
__constant__ int GRP_OFF[5] = {0, 8, 12, 20, 32};

__global__ void tooth_loss_kernel(const float* __restrict__ partials,
                                  float* __restrict__ out) {
    __shared__ double cx[NCH], cy[NCH], cz[NCH], vol[NCH];
    const int c = threadIdx.x;   // 64 threads = 1 wave; c == b*32 + t

    // per-channel totals: float4 loads over the 24 chunk-partials
    {
        double S = 0.0, WX = 0.0, WY = 0.0, WZ = 0.0;
        const floatx4* p = reinterpret_cast<const floatx4*>(partials)
                         + (size_t)c * CHUNKS;
        #pragma unroll
        for (int j = 0; j < CHUNKS; j++) {
            floatx4 v = p[j];
            S  += (double)v.x;
            WX += (double)v.y;
            WY += (double)v.z;
            WZ += (double)v.w;
        }
        vol[c] = S;
        double safe = (S > 0.0) ? S : 1.0;
        double ccx = WX / safe / (double)W_;
        double ccy = WY / safe / (double)H_;
        double ccz = WZ / safe / (double)D_;
        if (!(S > 0.0)) { ccx = 0.0; ccy = 0.0; ccz = 0.0; }
        cx[c] = ccx; cy[c] = ccy; cz[c] = ccz;
    }
    __syncthreads();

    double lm = 0.0, adj = 0.0, xya = 0.0, zh = 0.0,
           yza = 0.0, xsq = 0.0, an = 0.0;

    // landmark: one (b,t) per lane
    {
        int t = c & 31;
        double es = TRIG_S[t & 15], ec = TRIG_C[t & 15];
        double ex, ey, ez;
        if (t < 16) { ex = 0.6  * es; ey = -0.6  * ec; ez = 0.7; }   // upper
        else        { ex = 0.55 * es; ey =  0.55 * ec; ez = 0.3; }   // lower
        double dx = cx[c] - ex, dy = cy[c] - ey, dz = cz[c] - ez;
        lm = dx * dx + dy * dy + dz * dz;
    }

    // adjacent hinge: 2 halves x 14 pairs x 2 batches = 56 lanes
    if (c < 56) {
        int b = c & 1, p = c >> 1;                 // p in [0,28)
        int half = (p >= 14) ? 1 : 0;
        int i0 = p - half * 14;                    // [0,14)
        int i  = i0 + (i0 >= 7 ? 1 : 0);           // skip the 7->8 gap
        int i1 = b * 32 + half * 16 + i;           // pair (i1, i1+1)
        double dx = cx[i1] - cx[i1 + 1];
        double dy = cy[i1] - cy[i1 + 1];
        double dz = cz[i1] - cz[i1 + 1];
        double r = sqrt(dx * dx + dy * dy + dz * dz) - 0.1;
        adj = (r > 0.0) ? r : 0.0;
    }

    // opposing + symmetric (same index set): 2 halves x 8 x 2 batches = 32 lanes
    if (c < 32) {
        int b = c & 1, r = c >> 1;                 // r in [0,16)
        int half = r >> 3, i = r & 7;
        int i1 = b * 32 + half * 16 + i;
        int i2 = b * 32 + half * 16 + 15 - i;
        double dx = cx[i1] - cx[i2];
        double dy = cy[i1] - cy[i2];
        double dz = cz[i1] - cz[i2];
        xya = dx * dx + dy * dy;                   // opposing xy-MSE numerator
        double rz = 0.3 - fabs(dz);
        zh = (rz > 0.0) ? rz : 0.0;                // opposing z hinge
        yza = dy * dy + dz * dz;                   // symmetric yz-MSE numerator
        double sx = cx[i1] + cx[i2];
        xsq = sx * sx;                             // symmetric x term
    }

    // anatomy: 4 groups x 2 batches = 8 lanes; two-pass sample variance (ddof=1)
    if (c < 8) {
        int g = c >> 1, b = c & 1;
        int o0 = GRP_OFF[g], o1 = GRP_OFF[g + 1];
        int n = o1 - o0;
        double mean = 0.0;
        for (int k = o0; k < o1; k++) mean += vol[b * 32 + GRP_IDX[k]];
        mean /= (double)n;
        double ssd = 0.0;
        for (int k = o0; k < o1; k++) {
            double d = vol[b * 32 + GRP_IDX[k]] - mean;
            ssd += d * d;
        }
        an = ssd / (double)(n - 1);
    }

    // wave64 tree reduction of all 7 terms (all lanes participate)
    for (int off = 32; off > 0; off >>= 1) {
        lm  += __shfl_down(lm,  off, 64);
        adj += __shfl_down(adj, off, 64);
        xya += __shfl_down(xya, off, 64);
        zh  += __shfl_down(zh,  off, 64);
        yza += __shfl_down(yza, off, 64);
        xsq += __shfl_down(xsq, off, 64);
        an  += __shfl_down(an,  off, 64);
    }

    if (c == 0) {
        double landmark = lm / 192.0;                       // mean over (2,32,3)
        double spatial  = adj * 0.5 + xya * 0.25 + zh * 0.5;
        double symmetry = yza * 0.25 + xsq * 0.5;
        double anatomy  = an * 0.5;                         // mean over batch
        double L  = landmark * 10.0;
        double Sp = spatial  *  5.0;
        double Sy = symmetry *  3.0;
        double An = anatomy  *  7.0;
        out[0] = (float)L;
        out[1] = (float)Sp;
        out[2] = (float)Sy;
        out[3] = (float)An;
        out[4] = (float)(L + Sp + Sy + An);
    }
}

extern "C" void kernel_launch(void* const* d_in, const int* in_sizes, int n_in,
                              void* d_out, int out_size, void* d_ws, size_t ws_size,
                              hipStream_t stream) {
    const float* seg = (const float*)d_in[0];
    float* partials  = (float*)d_ws;       // 64 * 24 * 4 floats = 24 KB
    float* out       = (float*)d_out;

    dim3 grid(CHUNKS, NCH);                // 1536 blocks = 6 blocks/CU, zero tail
    tooth_reduce_kernel<<<grid, 256, 0, stream>>>(seg, partials);
    tooth_loss_kernel<<<1, 64, 0, stream>>>(partials, out);
}